// Round 13
// baseline (993736.119 us; speedup 1.0000x reference)
//
#include <hip/hip_runtime.h>

#define NB   128   // batch
#define NS   512   // sequence length
#define NF   512   // input features
#define NH   512   // hidden
#define KTOT 1024  // NF + NH (fused [x_t | h] GEMM K)
#define NTEAM 8    // independent batch-row teams (no cross-team sync)
#define WGT   32   // WGs per team (each owns 16 units x 4 gates)
#define ROWS  16   // batch rows per team
#define THR   256  // threads per WG (4 waves)
#define NWGS  (NTEAM * WGT)   // 256 WGs -> one per CU (proven residency)

typedef __attribute__((ext_vector_type(8))) short short8;
typedef __attribute__((ext_vector_type(4))) float floatx4;
typedef unsigned long long ull;

__device__ __forceinline__ unsigned short f2bf(float f) {
  union { float f; unsigned u; } v; v.f = f;
  return (unsigned short)((v.u + 0x7FFFu + ((v.u >> 16) & 1u)) >> 16);  // RNE
}
__device__ __forceinline__ float fsig(float v) { return 1.f / (1.f + __expf(-v)); }
__device__ __forceinline__ float ftanh(float v) {
  float e = __expf(2.f * fabsf(v));                 // inf-safe: 1 - 2/inf = 1
  return copysignf(1.f - 2.f / (e + 1.f), v);
}

// Pack W^T bf16 [2048 gate-cols][1024 K] : K = [input features | hidden units].
// Gate order g: 0=i,1=f,2=g,3=o. Also bsum[j] = b_i[j] + b_h[j].
__global__ void pack_weights(const float* __restrict__ wii, const float* __restrict__ whi,
                             const float* __restrict__ wif, const float* __restrict__ whf,
                             const float* __restrict__ wig, const float* __restrict__ whg,
                             const float* __restrict__ wio, const float* __restrict__ who,
                             const float* __restrict__ bii, const float* __restrict__ bhi,
                             const float* __restrict__ bif, const float* __restrict__ bhf,
                             const float* __restrict__ big_, const float* __restrict__ bhg,
                             const float* __restrict__ bio, const float* __restrict__ bho,
                             unsigned short* __restrict__ WT, float* __restrict__ bsum) {
  const int j = blockIdx.x;                // 0..2047
  const int g = j >> 9, u = j & 511;
  const float* Wi = (g == 0) ? wii : (g == 1) ? wif : (g == 2) ? wig : wio;
  const float* Wh = (g == 0) ? whi : (g == 1) ? whf : (g == 2) ? whg : who;
  unsigned short* row = WT + (size_t)j * KTOT;
  for (int k = threadIdx.x; k < KTOT; k += blockDim.x) {
    float v = (k < NF) ? Wi[(size_t)k * NH + u] : Wh[(size_t)(k - NF) * NH + u];
    row[k] = f2bf(v);
  }
  if (threadIdx.x == 0) {
    const float* bi = (g == 0) ? bii : (g == 1) ? bif : (g == 2) ? big_ : bio;
    const float* bh = (g == 0) ? bhi : (g == 1) ? bhf : (g == 2) ? bhg : bho;
    bsum[j] = bi[u] + bh[u];
  }
}

// Zero h0 (buffer 0), epoch flags, and the XCD-census area. Every launch.
__global__ void zero_state(unsigned short* __restrict__ hbf, unsigned* __restrict__ flags) {
  int i = blockIdx.x * blockDim.x + threadIdx.x;
  if (i < NB * NH) hbf[i] = 0;
  if (i < 2560) flags[i] = 0;   // 2048 epoch words + census masks/counters
}

#define LDW(i) short8 w##i = *(const short8*)(wrow + (i) * 32);
#define PIN4(a, b, c, d) asm volatile("" : "+v"(a), "+v"(b), "+v"(c), "+v"(d));

// One K=64 step: two 64B k-slices from panel P (swizzled rows).
#define KH(P, p, WA, WB)                                                        \
  do {                                                                          \
    short8 a0 = *(const short8*)((P) + (((p) * 128 + kb0) ^ swz));              \
    short8 a1 = *(const short8*)((P) + (((p) * 128 + 64 + kb0) ^ swz));         \
    acc0 = __builtin_amdgcn_mfma_f32_16x16x32_bf16(a0, WA, acc0, 0, 0, 0);      \
    acc1 = __builtin_amdgcn_mfma_f32_16x16x32_bf16(a1, WB, acc1, 0, 0, 0);      \
  } while (0);

#define CVT8(V, A, B)                                                          \
  { V[0] = (short)f2bf((A)[0]); V[1] = (short)f2bf((A)[1]);                    \
    V[2] = (short)f2bf((A)[2]); V[3] = (short)f2bf((A)[3]);                    \
    V[4] = (short)f2bf((B)[0]); V[5] = (short)f2bf((B)[1]);                    \
    V[6] = (short)f2bf((B)[2]); V[7] = (short)f2bf((B)[3]); }

// The sequential loop. Protocol byte-identical to the verified 1045us R12
// kernel (wave-0 poller, double-buffered sX, epoch flags, sG gate exchange,
// 4 barriers, split x-GEMM hiding the h-loads, plain launch). Single delta:
// x prefetch distance 2. x(t+1) is loaded during step t-1 and carried in
// registers across the whole step (~4900cyc of cover vs ~250 before), fully
// hiding the HBM/L3 x-load latency; the stage happens at the top of step t,
// then x(t+2) loads issue immediately.
// Watchdogs bound both spin loops (fast wrong-result FAIL, never a hang).
// FAST=true: team verified on ONE XCD -> sc0 (L1-bypass) L2 exchange.
template <bool FAST>
__device__ __forceinline__ void lstm_loop(
    const float* __restrict__ x, const unsigned short* __restrict__ WT,
    const float* __restrict__ bsum, unsigned short* __restrict__ hbf,
    unsigned* __restrict__ flags, float* __restrict__ out,
    unsigned char* sX, unsigned char* sH, float* sG) {
  const int tid  = threadIdx.x;
  const int lane = tid & 63;
  const int wv   = tid >> 6;          // 0..3
  const int gate = wv;                // one gate per wave
  const int team = blockIdx.x & 7;
  const int mem  = blockIdx.x >> 3;   // 0..31: member within team
  const int r0   = team * ROWS;
  const int U0   = mem * 16;
  const int lo16 = lane & 15;
  const int hi4  = lane >> 4;

  // ---- persistent weights: col j = gate*512 + U0 + lo16, K=1024 (32 short8)
  const unsigned short* wrow =
      WT + (size_t)(gate * NH + U0 + lo16) * KTOT + hi4 * 8;
  LDW(0)  LDW(1)  LDW(2)  LDW(3)  LDW(4)  LDW(5)  LDW(6)  LDW(7)
  LDW(8)  LDW(9)  LDW(10) LDW(11) LDW(12) LDW(13) LDW(14) LDW(15)
  LDW(16) LDW(17) LDW(18) LDW(19) LDW(20) LDW(21) LDW(22) LDW(23)
  LDW(24) LDW(25) LDW(26) LDW(27) LDW(28) LDW(29) LDW(30) LDW(31)
  PIN4(w0, w1, w2, w3)     PIN4(w4, w5, w6, w7)
  PIN4(w8, w9, w10, w11)   PIN4(w12, w13, w14, w15)
  PIN4(w16, w17, w18, w19) PIN4(w20, w21, w22, w23)
  PIN4(w24, w25, w26, w27) PIN4(w28, w29, w30, w31)

  // ---- staging geometry: thread owns 4 row-chunks (16B each) of the panel
  const int sr0 = wv;           // 0..3
  const int sr1 = wv + 4;
  const int sr2 = wv + 8;
  const int sr3 = wv + 12;
  const int soff0 = (lane * 16) ^ ((sr0 & 7) << 4);
  const int soff1 = (lane * 16) ^ ((sr1 & 7) << 4);
  const int soff2 = (lane * 16) ^ ((sr2 & 7) << 4);
  const int soff3 = (lane * 16) ^ ((sr3 & 7) << 4);
  const float* xb0 = x + (size_t)(r0 + sr0) * (NS * NF) + lane * 8;
  const float* xb1 = x + (size_t)(r0 + sr1) * (NS * NF) + lane * 8;
  const float* xb2 = x + (size_t)(r0 + sr2) * (NS * NF) + lane * 8;
  const float* xb3 = x + (size_t)(r0 + sr3) * (NS * NF) + lane * 8;
  const size_t ho0 = (size_t)(r0 + sr0) * NH + lane * 8;
  const size_t ho1 = (size_t)(r0 + sr1) * NH + lane * 8;
  const size_t ho2 = (size_t)(r0 + sr2) * NH + lane * 8;
  const size_t ho3 = (size_t)(r0 + sr3) * NH + lane * 8;

  // ---- cell-update mapping: 256 threads = 16 rows x 16 units, c in register
  const int crow = tid >> 4, cu = tid & 15;
  const float b0 = bsum[0 * NH + U0 + cu];
  const float b1 = bsum[1 * NH + U0 + cu];
  const float b2 = bsum[2 * NH + U0 + cu];
  const float b3 = bsum[3 * NH + U0 + cu];
  const size_t hidx = (size_t)(r0 + crow) * NH + (U0 + cu);
  float c_reg = 0.f;

  unsigned* tf = flags + team * WGT * 8;   // one 32B line per member

  const int kb0 = hi4 * 16;
  const int swz = (lo16 & 7) << 4;

  // ---- prologue: stage x(0) into panel 0; preload x(1) into registers
  {
    floatx4 a0 = *(const floatx4*)xb0, a1 = *(const floatx4*)(xb0 + 4);
    floatx4 a2 = *(const floatx4*)xb1, a3 = *(const floatx4*)(xb1 + 4);
    floatx4 a4 = *(const floatx4*)xb2, a5 = *(const floatx4*)(xb2 + 4);
    floatx4 a6 = *(const floatx4*)xb3, a7 = *(const floatx4*)(xb3 + 4);
    short8 v;
    CVT8(v, a0, a1) *(short8*)(sX + sr0 * 1024 + soff0) = v;
    CVT8(v, a2, a3) *(short8*)(sX + sr1 * 1024 + soff1) = v;
    CVT8(v, a4, a5) *(short8*)(sX + sr2 * 1024 + soff2) = v;
    CVT8(v, a6, a7) *(short8*)(sX + sr3 * 1024 + soff3) = v;
  }
  floatx4 xr0 = *(const floatx4*)(xb0 + NF);
  floatx4 xr1 = *(const floatx4*)(xb0 + NF + 4);
  floatx4 xr2 = *(const floatx4*)(xb1 + NF);
  floatx4 xr3 = *(const floatx4*)(xb1 + NF + 4);
  floatx4 xr4 = *(const floatx4*)(xb2 + NF);
  floatx4 xr5 = *(const floatx4*)(xb2 + NF + 4);
  floatx4 xr6 = *(const floatx4*)(xb3 + NF);
  floatx4 xr7 = *(const floatx4*)(xb3 + NF + 4);
  __syncthreads();

  float hn = 0.f;
  for (int t = 0; t < NS; ++t) {
    const unsigned short* hr = hbf + (t & 1) * (NB * NH);
    unsigned short*       hw = hbf + ((t + 1) & 1) * (NB * NH);
    unsigned char* Xcur = sX + (t & 1) * (ROWS * 1024);
    unsigned char* Xnxt = sX + ((t + 1) & 1) * (ROWS * 1024);

    // ---- stage x(t+1) (loaded one full step ago -> latency fully hidden)
    //      into Xnxt. Race-free: Xnxt was last read by x-GEMM(t-1), which
    //      finished before S2(t-1) -- three barriers before this write.
    {
      short8 v;
      CVT8(v, xr0, xr1) *(short8*)(Xnxt + sr0 * 1024 + soff0) = v;
      CVT8(v, xr2, xr3) *(short8*)(Xnxt + sr1 * 1024 + soff1) = v;
      CVT8(v, xr4, xr5) *(short8*)(Xnxt + sr2 * 1024 + soff2) = v;
      CVT8(v, xr6, xr7) *(short8*)(Xnxt + sr3 * 1024 + soff3) = v;
    }

    // ---- issue x(t+2) loads; consumed at the top of step t+1
    {
      const size_t tn = (size_t)((t + 2 < NS) ? t + 2 : NS - 1) * NF;
      xr0 = *(const floatx4*)(xb0 + tn);
      xr1 = *(const floatx4*)(xb0 + tn + 4);
      xr2 = *(const floatx4*)(xb1 + tn);
      xr3 = *(const floatx4*)(xb1 + tn + 4);
      xr4 = *(const floatx4*)(xb2 + tn);
      xr5 = *(const floatx4*)(xb2 + tn + 4);
      xr6 = *(const floatx4*)(xb3 + tn);
      xr7 = *(const floatx4*)(xb3 + tn + 4);
    }

    // ---- x-GEMM part 1 (K=0..255) from Xcur (staged last iteration)
    floatx4 acc0 = {0.f, 0.f, 0.f, 0.f};
    floatx4 acc1 = {0.f, 0.f, 0.f, 0.f};
    const unsigned char* Xa = Xcur + lo16 * 1024;
    {
      KH(Xa, 0, w0, w1)   KH(Xa, 1, w2, w3)   KH(Xa, 2, w4, w5)   KH(Xa, 3, w6, w7)
    }

    // ---- team barrier: lanes 0..31 of wave 0 poll 32 flag lines (watchdog'd)
    if (wv == 0) {
      int guard = 0;
      for (;;) {
        unsigned f = 0xFFFFFFFFu;
        if (lane < WGT) {
          if (FAST) {
            const unsigned* fp = tf + lane * 8;
            asm volatile("global_load_dword %0, %1, off sc0\n\t"
                         "s_waitcnt vmcnt(0)"
                         : "=v"(f) : "v"(fp) : "memory");
          } else {
            f = __hip_atomic_load(tf + lane * 8, __ATOMIC_RELAXED,
                                  __HIP_MEMORY_SCOPE_AGENT);
          }
        }
        if (__all(f >= (unsigned)t)) break;
        if (++guard > (1 << 14)) break;   // watchdog: fail fast, never hang
        __builtin_amdgcn_s_sleep(1);
      }
    }
    __syncthreads();                       // S1: team at epoch t
    asm volatile("" ::: "memory");

    // ---- issue h(t) loads (no wait) ...
    const unsigned short* hp0 = hr + ho0;
    const unsigned short* hp1 = hr + ho1;
    const unsigned short* hp2 = hr + ho2;
    const unsigned short* hp3 = hr + ho3;
    short8 hv0, hv1, hv2, hv3;
    if (FAST) {
      asm volatile("global_load_dwordx4 %0, %4, off sc0\n\t"
                   "global_load_dwordx4 %1, %5, off sc0\n\t"
                   "global_load_dwordx4 %2, %6, off sc0\n\t"
                   "global_load_dwordx4 %3, %7, off sc0"
                   : "=&v"(hv0), "=&v"(hv1), "=&v"(hv2), "=&v"(hv3)
                   : "v"(hp0), "v"(hp1), "v"(hp2), "v"(hp3) : "memory");
    } else {
      ull a0 = __hip_atomic_load((const ull*)hp0,     __ATOMIC_RELAXED, __HIP_MEMORY_SCOPE_AGENT);
      ull a1 = __hip_atomic_load((const ull*)hp0 + 1, __ATOMIC_RELAXED, __HIP_MEMORY_SCOPE_AGENT);
      ull a2 = __hip_atomic_load((const ull*)hp1,     __ATOMIC_RELAXED, __HIP_MEMORY_SCOPE_AGENT);
      ull a3 = __hip_atomic_load((const ull*)hp1 + 1, __ATOMIC_RELAXED, __HIP_MEMORY_SCOPE_AGENT);
      ull a4 = __hip_atomic_load((const ull*)hp2,     __ATOMIC_RELAXED, __HIP_MEMORY_SCOPE_AGENT);
      ull a5 = __hip_atomic_load((const ull*)hp2 + 1, __ATOMIC_RELAXED, __HIP_MEMORY_SCOPE_AGENT);
      ull a6 = __hip_atomic_load((const ull*)hp3,     __ATOMIC_RELAXED, __HIP_MEMORY_SCOPE_AGENT);
      ull a7 = __hip_atomic_load((const ull*)hp3 + 1, __ATOMIC_RELAXED, __HIP_MEMORY_SCOPE_AGENT);
      ((ull*)&hv0)[0] = a0; ((ull*)&hv0)[1] = a1;
      ((ull*)&hv1)[0] = a2; ((ull*)&hv1)[1] = a3;
      ((ull*)&hv2)[0] = a4; ((ull*)&hv2)[1] = a5;
      ((ull*)&hv3)[0] = a6; ((ull*)&hv3)[1] = a7;
    }

    // ---- ... x-GEMM part 2 (K=256..511) runs while the h loads fly
    {
      KH(Xa, 4, w8, w9)   KH(Xa, 5, w10, w11) KH(Xa, 6, w12, w13) KH(Xa, 7, w14, w15)
    }

    // ---- drain h loads, stage into sH
    if (FAST) { asm volatile("s_waitcnt vmcnt(0)" ::: "memory"); }
    *(short8*)(sH + sr0 * 1024 + soff0) = hv0;
    *(short8*)(sH + sr1 * 1024 + soff1) = hv1;
    *(short8*)(sH + sr2 * 1024 + soff2) = hv2;
    *(short8*)(sH + sr3 * 1024 + soff3) = hv3;
    __syncthreads();                       // S2: sH staged

    // ---- h-half GEMM
    {
      const unsigned char* Ha = sH + lo16 * 1024;
      KH(Ha, 0, w16, w17) KH(Ha, 1, w18, w19) KH(Ha, 2, w20, w21) KH(Ha, 3, w22, w23)
      KH(Ha, 4, w24, w25) KH(Ha, 5, w26, w27) KH(Ha, 6, w28, w29) KH(Ha, 7, w30, w31)
    }
    floatx4 acc = acc0 + acc1;

    // ---- gate exchange: D layout col=lane&15, row=(lane>>4)*4+reg
    {
      float* p = sG + (gate * 16 + lo16) * 17 + hi4 * 4;
      p[0] = acc[0]; p[1] = acc[1]; p[2] = acc[2]; p[3] = acc[3];
    }
    __syncthreads();                       // S3: all pre-acts in sG

    // ---- LSTM cell (fp32), one (row,unit) per thread, c in register
    float pi = sG[(0 * 16 + cu) * 17 + crow] + b0;
    float pf = sG[(1 * 16 + cu) * 17 + crow] + b1;
    float pg = sG[(2 * 16 + cu) * 17 + crow] + b2;
    float po = sG[(3 * 16 + cu) * 17 + crow] + b3;
    float ig = fsig(pi), fg = fsig(pf), gg = ftanh(pg), og = fsig(po);
    c_reg = fg * c_reg + ig * gg;
    hn = og * ftanh(c_reg);

    // pack 2 bf16 (even/odd unit) -> one 4B store
    unsigned hvv = f2bf(hn);
    unsigned ov = __shfl_xor(hvv, 1);
    if ((lane & 1) == 0) {
      unsigned* dst = (unsigned*)(hw + hidx);   // cu even -> 4B aligned
      unsigned val = hvv | (ov << 16);
      if (FAST) {
        asm volatile("global_store_dword %0, %1, off sc0" :: "v"(dst), "v"(val) : "memory");
      } else {
        __hip_atomic_store(dst, val, __ATOMIC_RELAXED, __HIP_MEMORY_SCOPE_AGENT);
      }
    }

    // ---- publish: drain stores, WG-barrier, bump this WG's epoch flag
    asm volatile("s_waitcnt vmcnt(0)" ::: "memory");
    __syncthreads();                       // S4: sG consumed + h stores drained
    if (tid == 0) {
      unsigned* fp = tf + mem * 8;
      unsigned ep = (unsigned)(t + 1);
      if (FAST) {
        asm volatile("global_store_dword %0, %1, off sc0" :: "v"(fp), "v"(ep) : "memory");
      } else {
        __hip_atomic_store(fp, ep, __ATOMIC_RELAXED, __HIP_MEMORY_SCOPE_AGENT);
      }
    }
  }

  // ---- final (h_T, c_T) -> d_out, fp32
  out[hidx] = hn;
  out[NB * NH + hidx] = c_reg;
}

// Kernel: XCD census (is my whole team on one XCD?) then run fast or safe loop.
__global__ __launch_bounds__(THR, 1)
void lstm_seq(const float* __restrict__ x, const unsigned short* __restrict__ WT,
              const float* __restrict__ bsum, unsigned short* __restrict__ hbf,
              unsigned* __restrict__ flags, float* __restrict__ out) {
  __shared__ __align__(16) unsigned char sX[2 * ROWS * 1024];  // x panels (dbuf)
  __shared__ __align__(16) unsigned char sH[ROWS * 1024];      // h panel
  __shared__ float sG[4 * 16 * 17];                            // gate pre-acts
  __shared__ int s_same;

  const int team = blockIdx.x & 7;
  if (threadIdx.x == 0) {
    unsigned xcc;
    asm volatile("s_getreg_b32 %0, hwreg(HW_REG_XCC_ID)" : "=s"(xcc));
    unsigned* xmask = flags + 2048 + team * 8;
    unsigned* xcnt  = flags + 2176 + team * 8;
    __hip_atomic_fetch_or(xmask, 1u << (xcc & 31), __ATOMIC_RELAXED,
                          __HIP_MEMORY_SCOPE_AGENT);
    __hip_atomic_fetch_add(xcnt, 1u, __ATOMIC_RELEASE, __HIP_MEMORY_SCOPE_AGENT);
    unsigned c;
    int guard = 0;
    do {
      c = __hip_atomic_load(xcnt, __ATOMIC_ACQUIRE, __HIP_MEMORY_SCOPE_AGENT);
      if (c < WGT) {
        if (++guard > (1 << 18)) break;   // watchdog: fall back to SAFE path
        __builtin_amdgcn_s_sleep(8);
      }
    } while (c < WGT);
    unsigned m = __hip_atomic_load(xmask, __ATOMIC_RELAXED, __HIP_MEMORY_SCOPE_AGENT);
    s_same = (c >= WGT) && (__popc(m) == 1);
  }
  __syncthreads();

  if (s_same)
    lstm_loop<true>(x, WT, bsum, hbf, flags, out, sX, sH, sG);
  else
    lstm_loop<false>(x, WT, bsum, hbf, flags, out, sX, sH, sG);
}

extern "C" void kernel_launch(void* const* d_in, const int* in_sizes, int n_in,
                              void* d_out, int out_size, void* d_ws, size_t ws_size,
                              hipStream_t stream) {
  const float* x    = (const float*)d_in[0];
  const float* wii  = (const float*)d_in[1];
  const float* whi  = (const float*)d_in[2];
  const float* bii  = (const float*)d_in[3];
  const float* bhi  = (const float*)d_in[4];
  const float* wif  = (const float*)d_in[5];
  const float* whf  = (const float*)d_in[6];
  const float* bif  = (const float*)d_in[7];
  const float* bhf  = (const float*)d_in[8];
  const float* wig  = (const float*)d_in[9];
  const float* whg  = (const float*)d_in[10];
  const float* big_ = (const float*)d_in[11];
  const float* bhg  = (const float*)d_in[12];
  const float* wio  = (const float*)d_in[13];
  const float* who  = (const float*)d_in[14];
  const float* bio  = (const float*)d_in[15];
  const float* bho  = (const float*)d_in[16];

  unsigned char* ws = (unsigned char*)d_ws;
  unsigned short* WT    = (unsigned short*)(ws);                     // 4 MiB
  float*          bsum  = (float*)(ws + 4194304);                    // 8 KiB
  unsigned short* hbf   = (unsigned short*)(ws + 4194304 + 8192);    // 256 KiB
  unsigned*       flags = (unsigned*)(ws + 4194304 + 8192 + 262144); // 10 KiB

  float* out = (float*)d_out;

  pack_weights<<<dim3(2048), dim3(256), 0, stream>>>(
      wii, whi, wif, whf, wig, whg, wio, who,
      bii, bhi, bif, bhf, big_, bhg, bio, bho, WT, bsum);
  zero_state<<<dim3(256), dim3(256), 0, stream>>>(hbf, flags);

  // Plain launch (coop launch rejects >128-WG grids on this stack; the
  // epoch-flag protocol needs only co-residency: 256 x 4-wave blocks at
  // ~53 KB LDS = 1 block/CU). Watchdogs turn any residency pathology into
  // a fast visible FAIL instead of a hang.
  lstm_seq<<<dim3(NWGS), dim3(THR), 0, stream>>>(x, WT, bsum, hbf, flags, out);
}

// Round 15
// 1044.492 us; speedup vs baseline: 951.4058x; 951.4058x over previous
//
#include <hip/hip_runtime.h>

#define NB   128   // batch
#define NS   512   // sequence length
#define NF   512   // input features
#define NH   512   // hidden
#define KTOT 1024  // NF + NH (fused [x_t | h] GEMM K)
#define NTEAM 8    // independent batch-row teams (no cross-team sync)
#define WGT   32   // WGs per team (each owns 16 units x 4 gates)
#define ROWS  16   // batch rows per team
#define THR   256  // threads per WG (4 waves)
#define NWGS  (NTEAM * WGT)   // 256 WGs -> one per CU (proven residency)

typedef __attribute__((ext_vector_type(8))) short short8;
typedef __attribute__((ext_vector_type(4))) float floatx4;
typedef unsigned long long ull;

__device__ __forceinline__ unsigned short f2bf(float f) {
  union { float f; unsigned u; } v; v.f = f;
  return (unsigned short)((v.u + 0x7FFFu + ((v.u >> 16) & 1u)) >> 16);  // RNE
}
__device__ __forceinline__ float fsig(float v) { return 1.f / (1.f + __expf(-v)); }
__device__ __forceinline__ float ftanh(float v) {
  float e = __expf(2.f * fabsf(v));                 // inf-safe: 1 - 2/inf = 1
  return copysignf(1.f - 2.f / (e + 1.f), v);
}

// Pack W^T bf16 [2048 gate-cols][1024 K] : K = [input features | hidden units].
// Gate order g: 0=i,1=f,2=g,3=o. Also bsum[j] = b_i[j] + b_h[j].
__global__ void pack_weights(const float* __restrict__ wii, const float* __restrict__ whi,
                             const float* __restrict__ wif, const float* __restrict__ whf,
                             const float* __restrict__ wig, const float* __restrict__ whg,
                             const float* __restrict__ wio, const float* __restrict__ who,
                             const float* __restrict__ bii, const float* __restrict__ bhi,
                             const float* __restrict__ bif, const float* __restrict__ bhf,
                             const float* __restrict__ big_, const float* __restrict__ bhg,
                             const float* __restrict__ bio, const float* __restrict__ bho,
                             unsigned short* __restrict__ WT, float* __restrict__ bsum) {
  const int j = blockIdx.x;                // 0..2047
  const int g = j >> 9, u = j & 511;
  const float* Wi = (g == 0) ? wii : (g == 1) ? wif : (g == 2) ? wig : wio;
  const float* Wh = (g == 0) ? whi : (g == 1) ? whf : (g == 2) ? whg : who;
  unsigned short* row = WT + (size_t)j * KTOT;
  for (int k = threadIdx.x; k < KTOT; k += blockDim.x) {
    float v = (k < NF) ? Wi[(size_t)k * NH + u] : Wh[(size_t)(k - NF) * NH + u];
    row[k] = f2bf(v);
  }
  if (threadIdx.x == 0) {
    const float* bi = (g == 0) ? bii : (g == 1) ? bif : (g == 2) ? big_ : bio;
    const float* bh = (g == 0) ? bhi : (g == 1) ? bhf : (g == 2) ? bhg : bho;
    bsum[j] = bi[u] + bh[u];
  }
}

// Zero h0 (buffer 0), epoch flags, and the XCD-census area. Every launch.
__global__ void zero_state(unsigned short* __restrict__ hbf, unsigned* __restrict__ flags) {
  int i = blockIdx.x * blockDim.x + threadIdx.x;
  if (i < NB * NH) hbf[i] = 0;
  if (i < 2560) flags[i] = 0;   // 2048 epoch words + census masks/counters
}

#define LDW(i) short8 w##i = *(const short8*)(wrow + (i) * 32);
#define PIN4(a, b, c, d) asm volatile("" : "+v"(a), "+v"(b), "+v"(c), "+v"(d));

// One K=64 step: two 64B k-slices from panel P (swizzled rows).
#define KH(P, p, WA, WB)                                                        \
  do {                                                                          \
    short8 a0 = *(const short8*)((P) + (((p) * 128 + kb0) ^ swz));              \
    short8 a1 = *(const short8*)((P) + (((p) * 128 + 64 + kb0) ^ swz));         \
    acc0 = __builtin_amdgcn_mfma_f32_16x16x32_bf16(a0, WA, acc0, 0, 0, 0);      \
    acc1 = __builtin_amdgcn_mfma_f32_16x16x32_bf16(a1, WB, acc1, 0, 0, 0);      \
  } while (0);

#define CVT8(V, A, B)                                                          \
  { V[0] = (short)f2bf((A)[0]); V[1] = (short)f2bf((A)[1]);                    \
    V[2] = (short)f2bf((A)[2]); V[3] = (short)f2bf((A)[3]);                    \
    V[4] = (short)f2bf((B)[0]); V[5] = (short)f2bf((B)[1]);                    \
    V[6] = (short)f2bf((B)[2]); V[7] = (short)f2bf((B)[3]); }

// The sequential loop. Verified R12 structure (1045us): wave-0 poller,
// double-buffered sX, epoch flags, sG gate exchange, 4 barriers, plain
// launch. The x-GEMM is split in half around the poll: phase B issues the
// h(t) loads FIRST (no waitcnt), then runs x-GEMM K=256..511 while the
// loads are in flight, then drains vmcnt and stages sH -- hiding the
// ~300-500cyc L2 h-load latency under independent MFMA work. x(t+1) loads
// are issued at the top of the step and consumed (cvt+LDS-stage) BEFORE the
// poll -- register-carried state must not span the poll (R13 lesson: a
// loop-carried x prefetch made the poll watchdog-trip every step, 1000x).
// Watchdogs bound both spin loops (fast wrong-result FAIL, never a hang).
// FAST=true: team verified on ONE XCD -> sc0 (L1-bypass) L2 exchange.
template <bool FAST>
__device__ __forceinline__ void lstm_loop(
    const float* __restrict__ x, const unsigned short* __restrict__ WT,
    const float* __restrict__ bsum, unsigned short* __restrict__ hbf,
    unsigned* __restrict__ flags, float* __restrict__ out,
    unsigned char* sX, unsigned char* sH, float* sG) {
  const int tid  = threadIdx.x;
  const int lane = tid & 63;
  const int wv   = tid >> 6;          // 0..3
  const int gate = wv;                // one gate per wave
  const int team = blockIdx.x & 7;
  const int mem  = blockIdx.x >> 3;   // 0..31: member within team
  const int r0   = team * ROWS;
  const int U0   = mem * 16;
  const int lo16 = lane & 15;
  const int hi4  = lane >> 4;

  // ---- persistent weights: col j = gate*512 + U0 + lo16, K=1024 (32 short8)
  const unsigned short* wrow =
      WT + (size_t)(gate * NH + U0 + lo16) * KTOT + hi4 * 8;
  LDW(0)  LDW(1)  LDW(2)  LDW(3)  LDW(4)  LDW(5)  LDW(6)  LDW(7)
  LDW(8)  LDW(9)  LDW(10) LDW(11) LDW(12) LDW(13) LDW(14) LDW(15)
  LDW(16) LDW(17) LDW(18) LDW(19) LDW(20) LDW(21) LDW(22) LDW(23)
  LDW(24) LDW(25) LDW(26) LDW(27) LDW(28) LDW(29) LDW(30) LDW(31)
  PIN4(w0, w1, w2, w3)     PIN4(w4, w5, w6, w7)
  PIN4(w8, w9, w10, w11)   PIN4(w12, w13, w14, w15)
  PIN4(w16, w17, w18, w19) PIN4(w20, w21, w22, w23)
  PIN4(w24, w25, w26, w27) PIN4(w28, w29, w30, w31)

  // ---- staging geometry: thread owns 4 row-chunks (16B each) of the panel
  const int sr0 = wv;           // 0..3
  const int sr1 = wv + 4;
  const int sr2 = wv + 8;
  const int sr3 = wv + 12;
  const int soff0 = (lane * 16) ^ ((sr0 & 7) << 4);
  const int soff1 = (lane * 16) ^ ((sr1 & 7) << 4);
  const int soff2 = (lane * 16) ^ ((sr2 & 7) << 4);
  const int soff3 = (lane * 16) ^ ((sr3 & 7) << 4);
  const float* xb0 = x + (size_t)(r0 + sr0) * (NS * NF) + lane * 8;
  const float* xb1 = x + (size_t)(r0 + sr1) * (NS * NF) + lane * 8;
  const float* xb2 = x + (size_t)(r0 + sr2) * (NS * NF) + lane * 8;
  const float* xb3 = x + (size_t)(r0 + sr3) * (NS * NF) + lane * 8;
  const size_t ho0 = (size_t)(r0 + sr0) * NH + lane * 8;
  const size_t ho1 = (size_t)(r0 + sr1) * NH + lane * 8;
  const size_t ho2 = (size_t)(r0 + sr2) * NH + lane * 8;
  const size_t ho3 = (size_t)(r0 + sr3) * NH + lane * 8;

  // ---- cell-update mapping: 256 threads = 16 rows x 16 units, c in register
  const int crow = tid >> 4, cu = tid & 15;
  const float b0 = bsum[0 * NH + U0 + cu];
  const float b1 = bsum[1 * NH + U0 + cu];
  const float b2 = bsum[2 * NH + U0 + cu];
  const float b3 = bsum[3 * NH + U0 + cu];
  const size_t hidx = (size_t)(r0 + crow) * NH + (U0 + cu);
  float c_reg = 0.f;

  unsigned* tf = flags + team * WGT * 8;   // one 32B line per member

  const int kb0 = hi4 * 16;
  const int swz = (lo16 & 7) << 4;

  // ---- prologue: stage x(0) into panel 0
  {
    floatx4 a0 = *(const floatx4*)xb0, a1 = *(const floatx4*)(xb0 + 4);
    floatx4 a2 = *(const floatx4*)xb1, a3 = *(const floatx4*)(xb1 + 4);
    floatx4 a4 = *(const floatx4*)xb2, a5 = *(const floatx4*)(xb2 + 4);
    floatx4 a6 = *(const floatx4*)xb3, a7 = *(const floatx4*)(xb3 + 4);
    short8 v;
    CVT8(v, a0, a1) *(short8*)(sX + sr0 * 1024 + soff0) = v;
    CVT8(v, a2, a3) *(short8*)(sX + sr1 * 1024 + soff1) = v;
    CVT8(v, a4, a5) *(short8*)(sX + sr2 * 1024 + soff2) = v;
    CVT8(v, a6, a7) *(short8*)(sX + sr3 * 1024 + soff3) = v;
  }
  __syncthreads();

  float hn = 0.f;
  for (int t = 0; t < NS; ++t) {
    const unsigned short* hr = hbf + (t & 1) * (NB * NH);
    unsigned short*       hw = hbf + ((t + 1) & 1) * (NB * NH);
    unsigned char* Xcur = sX + (t & 1) * (ROWS * 1024);
    unsigned char* Xnxt = sX + ((t + 1) & 1) * (ROWS * 1024);

    // ---- issue x(t+1) loads NOW; latency hides under the x-GEMM
    const size_t tn = (size_t)((t + 1 < NS) ? t + 1 : t) * NF;
    floatx4 xr0 = *(const floatx4*)(xb0 + tn);
    floatx4 xr1 = *(const floatx4*)(xb0 + tn + 4);
    floatx4 xr2 = *(const floatx4*)(xb1 + tn);
    floatx4 xr3 = *(const floatx4*)(xb1 + tn + 4);
    floatx4 xr4 = *(const floatx4*)(xb2 + tn);
    floatx4 xr5 = *(const floatx4*)(xb2 + tn + 4);
    floatx4 xr6 = *(const floatx4*)(xb3 + tn);
    floatx4 xr7 = *(const floatx4*)(xb3 + tn + 4);

    // ---- x-GEMM part 1 (K=0..255) from Xcur (staged last iteration)
    floatx4 acc0 = {0.f, 0.f, 0.f, 0.f};
    floatx4 acc1 = {0.f, 0.f, 0.f, 0.f};
    const unsigned char* Xa = Xcur + lo16 * 1024;
    {
      KH(Xa, 0, w0, w1)   KH(Xa, 1, w2, w3)   KH(Xa, 2, w4, w5)   KH(Xa, 3, w6, w7)
    }

    // ---- stage x(t+1) into the other panel NOW (pre-barrier; race-free:
    //      Xnxt was last read by x-GEMM(t-1), drained before S1(t-1)).
    {
      short8 v;
      CVT8(v, xr0, xr1) *(short8*)(Xnxt + sr0 * 1024 + soff0) = v;
      CVT8(v, xr2, xr3) *(short8*)(Xnxt + sr1 * 1024 + soff1) = v;
      CVT8(v, xr4, xr5) *(short8*)(Xnxt + sr2 * 1024 + soff2) = v;
      CVT8(v, xr6, xr7) *(short8*)(Xnxt + sr3 * 1024 + soff3) = v;
    }

    // ---- team barrier: lanes 0..31 of wave 0 poll 32 flag lines (watchdog'd)
    if (wv == 0) {
      int guard = 0;
      for (;;) {
        unsigned f = 0xFFFFFFFFu;
        if (lane < WGT) {
          if (FAST) {
            const unsigned* fp = tf + lane * 8;
            asm volatile("global_load_dword %0, %1, off sc0\n\t"
                         "s_waitcnt vmcnt(0)"
                         : "=v"(f) : "v"(fp) : "memory");
          } else {
            f = __hip_atomic_load(tf + lane * 8, __ATOMIC_RELAXED,
                                  __HIP_MEMORY_SCOPE_AGENT);
          }
        }
        if (__all(f >= (unsigned)t)) break;
        if (++guard > (1 << 14)) break;   // watchdog: fail fast, never hang
        __builtin_amdgcn_s_sleep(1);
      }
    }
    __syncthreads();                       // S1: team at epoch t
    asm volatile("" ::: "memory");

    // ---- issue h(t) loads (no wait) ...
    const unsigned short* hp0 = hr + ho0;
    const unsigned short* hp1 = hr + ho1;
    const unsigned short* hp2 = hr + ho2;
    const unsigned short* hp3 = hr + ho3;
    short8 hv0, hv1, hv2, hv3;
    if (FAST) {
      asm volatile("global_load_dwordx4 %0, %4, off sc0\n\t"
                   "global_load_dwordx4 %1, %5, off sc0\n\t"
                   "global_load_dwordx4 %2, %6, off sc0\n\t"
                   "global_load_dwordx4 %3, %7, off sc0"
                   : "=&v"(hv0), "=&v"(hv1), "=&v"(hv2), "=&v"(hv3)
                   : "v"(hp0), "v"(hp1), "v"(hp2), "v"(hp3) : "memory");
    } else {
      ull a0 = __hip_atomic_load((const ull*)hp0,     __ATOMIC_RELAXED, __HIP_MEMORY_SCOPE_AGENT);
      ull a1 = __hip_atomic_load((const ull*)hp0 + 1, __ATOMIC_RELAXED, __HIP_MEMORY_SCOPE_AGENT);
      ull a2 = __hip_atomic_load((const ull*)hp1,     __ATOMIC_RELAXED, __HIP_MEMORY_SCOPE_AGENT);
      ull a3 = __hip_atomic_load((const ull*)hp1 + 1, __ATOMIC_RELAXED, __HIP_MEMORY_SCOPE_AGENT);
      ull a4 = __hip_atomic_load((const ull*)hp2,     __ATOMIC_RELAXED, __HIP_MEMORY_SCOPE_AGENT);
      ull a5 = __hip_atomic_load((const ull*)hp2 + 1, __ATOMIC_RELAXED, __HIP_MEMORY_SCOPE_AGENT);
      ull a6 = __hip_atomic_load((const ull*)hp3,     __ATOMIC_RELAXED, __HIP_MEMORY_SCOPE_AGENT);
      ull a7 = __hip_atomic_load((const ull*)hp3 + 1, __ATOMIC_RELAXED, __HIP_MEMORY_SCOPE_AGENT);
      ((ull*)&hv0)[0] = a0; ((ull*)&hv0)[1] = a1;
      ((ull*)&hv1)[0] = a2; ((ull*)&hv1)[1] = a3;
      ((ull*)&hv2)[0] = a4; ((ull*)&hv2)[1] = a5;
      ((ull*)&hv3)[0] = a6; ((ull*)&hv3)[1] = a7;
    }

    // ---- ... x-GEMM part 2 (K=256..511) runs while the h loads fly
    {
      KH(Xa, 4, w8, w9)   KH(Xa, 5, w10, w11) KH(Xa, 6, w12, w13) KH(Xa, 7, w14, w15)
    }

    // ---- drain h loads, stage into sH
    if (FAST) { asm volatile("s_waitcnt vmcnt(0)" ::: "memory"); }
    *(short8*)(sH + sr0 * 1024 + soff0) = hv0;
    *(short8*)(sH + sr1 * 1024 + soff1) = hv1;
    *(short8*)(sH + sr2 * 1024 + soff2) = hv2;
    *(short8*)(sH + sr3 * 1024 + soff3) = hv3;
    __syncthreads();                       // S2: sH staged

    // ---- h-half GEMM
    {
      const unsigned char* Ha = sH + lo16 * 1024;
      KH(Ha, 0, w16, w17) KH(Ha, 1, w18, w19) KH(Ha, 2, w20, w21) KH(Ha, 3, w22, w23)
      KH(Ha, 4, w24, w25) KH(Ha, 5, w26, w27) KH(Ha, 6, w28, w29) KH(Ha, 7, w30, w31)
    }
    floatx4 acc = acc0 + acc1;

    // ---- gate exchange: D layout col=lane&15, row=(lane>>4)*4+reg
    {
      float* p = sG + (gate * 16 + lo16) * 17 + hi4 * 4;
      p[0] = acc[0]; p[1] = acc[1]; p[2] = acc[2]; p[3] = acc[3];
    }
    __syncthreads();                       // S3: all pre-acts in sG

    // ---- LSTM cell (fp32), one (row,unit) per thread, c in register
    float pi = sG[(0 * 16 + cu) * 17 + crow] + b0;
    float pf = sG[(1 * 16 + cu) * 17 + crow] + b1;
    float pg = sG[(2 * 16 + cu) * 17 + crow] + b2;
    float po = sG[(3 * 16 + cu) * 17 + crow] + b3;
    float ig = fsig(pi), fg = fsig(pf), gg = ftanh(pg), og = fsig(po);
    c_reg = fg * c_reg + ig * gg;
    hn = og * ftanh(c_reg);

    // pack 2 bf16 (even/odd unit) -> one 4B store
    unsigned hvv = f2bf(hn);
    unsigned ov = __shfl_xor(hvv, 1);
    if ((lane & 1) == 0) {
      unsigned* dst = (unsigned*)(hw + hidx);   // cu even -> 4B aligned
      unsigned val = hvv | (ov << 16);
      if (FAST) {
        asm volatile("global_store_dword %0, %1, off sc0" :: "v"(dst), "v"(val) : "memory");
      } else {
        __hip_atomic_store(dst, val, __ATOMIC_RELAXED, __HIP_MEMORY_SCOPE_AGENT);
      }
    }

    // ---- publish: drain stores, WG-barrier, bump this WG's epoch flag
    asm volatile("s_waitcnt vmcnt(0)" ::: "memory");
    __syncthreads();                       // S4: sG consumed + h stores drained
    if (tid == 0) {
      unsigned* fp = tf + mem * 8;
      unsigned ep = (unsigned)(t + 1);
      if (FAST) {
        asm volatile("global_store_dword %0, %1, off sc0" :: "v"(fp), "v"(ep) : "memory");
      } else {
        __hip_atomic_store(fp, ep, __ATOMIC_RELAXED, __HIP_MEMORY_SCOPE_AGENT);
      }
    }
  }

  // ---- final (h_T, c_T) -> d_out, fp32
  out[hidx] = hn;
  out[NB * NH + hidx] = c_reg;
}

// Kernel: XCD census (is my whole team on one XCD?) then run fast or safe loop.
__global__ __launch_bounds__(THR, 1)
void lstm_seq(const float* __restrict__ x, const unsigned short* __restrict__ WT,
              const float* __restrict__ bsum, unsigned short* __restrict__ hbf,
              unsigned* __restrict__ flags, float* __restrict__ out) {
  __shared__ __align__(16) unsigned char sX[2 * ROWS * 1024];  // x panels (dbuf)
  __shared__ __align__(16) unsigned char sH[ROWS * 1024];      // h panel
  __shared__ float sG[4 * 16 * 17];                            // gate pre-acts
  __shared__ int s_same;

  const int team = blockIdx.x & 7;
  if (threadIdx.x == 0) {
    unsigned xcc;
    asm volatile("s_getreg_b32 %0, hwreg(HW_REG_XCC_ID)" : "=s"(xcc));
    unsigned* xmask = flags + 2048 + team * 8;
    unsigned* xcnt  = flags + 2176 + team * 8;
    __hip_atomic_fetch_or(xmask, 1u << (xcc & 31), __ATOMIC_RELAXED,
                          __HIP_MEMORY_SCOPE_AGENT);
    __hip_atomic_fetch_add(xcnt, 1u, __ATOMIC_RELEASE, __HIP_MEMORY_SCOPE_AGENT);
    unsigned c;
    int guard = 0;
    do {
      c = __hip_atomic_load(xcnt, __ATOMIC_ACQUIRE, __HIP_MEMORY_SCOPE_AGENT);
      if (c < WGT) {
        if (++guard > (1 << 18)) break;   // watchdog: fall back to SAFE path
        __builtin_amdgcn_s_sleep(8);
      }
    } while (c < WGT);
    unsigned m = __hip_atomic_load(xmask, __ATOMIC_RELAXED, __HIP_MEMORY_SCOPE_AGENT);
    s_same = (c >= WGT) && (__popc(m) == 1);
  }
  __syncthreads();

  if (s_same)
    lstm_loop<true>(x, WT, bsum, hbf, flags, out, sX, sH, sG);
  else
    lstm_loop<false>(x, WT, bsum, hbf, flags, out, sX, sH, sG);
}

extern "C" void kernel_launch(void* const* d_in, const int* in_sizes, int n_in,
                              void* d_out, int out_size, void* d_ws, size_t ws_size,
                              hipStream_t stream) {
  const float* x    = (const float*)d_in[0];
  const float* wii  = (const float*)d_in[1];
  const float* whi  = (const float*)d_in[2];
  const float* bii  = (const float*)d_in[3];
  const float* bhi  = (const float*)d_in[4];
  const float* wif  = (const float*)d_in[5];
  const float* whf  = (const float*)d_in[6];
  const float* bif  = (const float*)d_in[7];
  const float* bhf  = (const float*)d_in[8];
  const float* wig  = (const float*)d_in[9];
  const float* whg  = (const float*)d_in[10];
  const float* big_ = (const float*)d_in[11];
  const float* bhg  = (const float*)d_in[12];
  const float* wio  = (const float*)d_in[13];
  const float* who  = (const float*)d_in[14];
  const float* bio  = (const float*)d_in[15];
  const float* bho  = (const float*)d_in[16];

  unsigned char* ws = (unsigned char*)d_ws;
  unsigned short* WT    = (unsigned short*)(ws);                     // 4 MiB
  float*          bsum  = (float*)(ws + 4194304);                    // 8 KiB
  unsigned short* hbf   = (unsigned short*)(ws + 4194304 + 8192);    // 256 KiB
  unsigned*       flags = (unsigned*)(ws + 4194304 + 8192 + 262144); // 10 KiB

  float* out = (float*)d_out;

  pack_weights<<<dim3(2048), dim3(256), 0, stream>>>(
      wii, whi, wif, whf, wig, whg, wio, who,
      bii, bhi, bif, bhf, big_, bhg, bio, bho, WT, bsum);
  zero_state<<<dim3(256), dim3(256), 0, stream>>>(hbf, flags);

  // Plain launch (coop launch rejects >128-WG grids on this stack; the
  // epoch-flag protocol needs only co-residency: 256 x 4-wave blocks at
  // ~53 KB LDS = 1 block/CU). Watchdogs turn any residency pathology into
  // a fast visible FAIL instead of a hang.
  lstm_seq<<<dim3(NWGS), dim3(THR), 0, stream>>>(x, WT, bsum, hbf, flags, out);
}